// Round 7
// baseline (112.069 us; speedup 1.0000x reference)
//
#include <hip/hip_runtime.h>
#include <math.h>

#define HID 128
#define CIN 64
#define NB 8
#define HD 128
#define WD 128
#define HW (HD*WD)   // 16384

typedef float v2f __attribute__((ext_vector_type(2)));
typedef _Float16 h2 __attribute__((ext_vector_type(2)));
typedef _Float16 h4 __attribute__((ext_vector_type(4)));

// ======= L1: fused gate + in-block h-scan =======
// Per block (bx, og, b): the 1024-px tile = 8 complete rows x 16 channels.
//   - inline bilinear upsample of its 4 px (og==0 blocks persist to out1)
//   - gamma==0: copy x slab -> out0 and exit
//   - compose Wd' = W_delta.W_in, Wb' = W_B.W_in (16-row slice) + biases into LDS
//   - 3 GEMVs (K=64) from x, packed fp32
//   - elementwise gate -> Abar, bbuf; h-scan (32-lane segmented shuffle) -> hsum
__global__ __launch_bounds__(256, 2) void gate_kernel(const float* __restrict__ x,
                                                      const float* __restrict__ prior,
                                                      const float* __restrict__ W_in,
                                                      const float* __restrict__ b_in,
                                                      const float* __restrict__ W_delta,
                                                      const float* __restrict__ b_delta,
                                                      const float* __restrict__ W_B,
                                                      const float* __restrict__ b_B,
                                                      const float* __restrict__ lam_p,
                                                      const float* __restrict__ alpha_p,
                                                      const float* __restrict__ A,
                                                      const float* __restrict__ gamma_p,
                                                      _Float16* __restrict__ Abar,
                                                      _Float16* __restrict__ bbuf,
                                                      _Float16* __restrict__ hsum,
                                                      float* __restrict__ out0,
                                                      float* __restrict__ out1) {
    __shared__ float sw[CIN][48];                          // {W_in | Wd' | Wb'} x 16 outs, 12 KB
    __shared__ float sbd[16], sbb[16], snA[16], sbi[16];
    const int bx = blockIdx.x, og = blockIdx.y, b = blockIdx.z;
    const int tid = threadIdx.x;
    const int p0 = bx * 1024 + tid * 4;
    const float g = gamma_p[0];

    // ---- inline prior upsample for this thread's 4 px (same row) ----
    const float scale = 63.0f / 127.0f;
    int i = p0 >> 7;
    float ys = i * scale;
    int y0 = (int)floorf(ys); int y1 = min(y0 + 1, 63);
    float wy = ys - (float)y0;
    const float* pp = prior + b * 4096;
    int col0 = p0 & 127;
    float pus[4];
#pragma unroll
    for (int k = 0; k < 4; ++k) {
        float xs = (col0 + k) * scale;
        int x0 = (int)floorf(xs); int x1 = min(x0 + 1, 63);
        float wx = xs - (float)x0;
        float v00 = pp[y0 * 64 + x0], v01 = pp[y0 * 64 + x1];
        float v10 = pp[y1 * 64 + x0], v11 = pp[y1 * 64 + x1];
        float r0 = v00 * (1.f - wy) + v10 * wy;
        float r1 = v01 * (1.f - wy) + v11 * wy;
        float v = r0 * (1.f - wx) + r1 * wx;
        pus[k] = fminf(fmaxf(v, -1.f), 1.f);
    }
    if (og == 0)
        *(float4*)(out1 + b * HW + p0) = make_float4(pus[0], pus[1], pus[2], pus[3]);

    // ---- gamma==0: out0 = x (this block's 8-channel slab), done ----
    if (g == 0.f) {
        const float* xs0 = x + b * (CIN * HW) + (og * 8) * HW + p0;
        float* o0 = out0 + b * (CIN * HW) + (og * 8) * HW + p0;
#pragma unroll
        for (int ch = 0; ch < 8; ++ch)
            *(float4*)(o0 + ch * HW) = *(const float4*)(xs0 + ch * HW);
        return;
    }

    // ---- compose weights for this block's 16 out-channels into LDS ----
#pragma unroll
    for (int k = 0; k < 4; ++k) {
        int e = tid + k * 256;                             // [0,1024): c = e>>4, j = e&15
        int c = e >> 4, j = e & 15;
        int o = og * 16 + j;
        float wd = 0.f, wb = 0.f;
        for (int h = 0; h < HID; ++h) {
            float wi = W_in[h * CIN + c];
            wd = fmaf(W_delta[o * HID + h], wi, wd);
            wb = fmaf(W_B[o * HID + h], wi, wb);
        }
        sw[c][j]      = W_in[o * CIN + c];
        sw[c][16 + j] = wd;
        sw[c][32 + j] = wb;
    }
    if (tid < 16) {
        int o = og * 16 + tid;
        float sd = b_delta[o], sb = b_B[o];
        for (int h = 0; h < HID; ++h) {
            float bi = b_in[h];
            sd = fmaf(W_delta[o * HID + h], bi, sd);
            sb = fmaf(W_B[o * HID + h], bi, sb);
        }
        sbd[tid] = sd; sbb[tid] = sb;
        snA[tid] = -expf(A[o]); sbi[tid] = b_in[o];
    }
    __syncthreads();

    // ---- main GEMV loop (K=64), packed fp32 ----
    v2f ai[16][2], ad[16][2], ab[16][2];
#pragma unroll
    for (int j = 0; j < 16; ++j)
#pragma unroll
        for (int k = 0; k < 2; ++k) {
            ai[j][k] = (v2f){0.f, 0.f};
            ad[j][k] = (v2f){0.f, 0.f};
            ab[j][k] = (v2f){0.f, 0.f};
        }

    const float* xb = x + b * (CIN * HW) + p0;
    for (int c = 0; c < CIN; ++c) {
        float4 xv = *(const float4*)(xb + c * HW);
        v2f xlo = (v2f){xv.x, xv.y};
        v2f xhi = (v2f){xv.z, xv.w};
        const float* w = sw[c];
#pragma unroll
        for (int j = 0; j < 16; ++j) {
            v2f wi = (v2f){w[j],      w[j]};
            v2f wd = (v2f){w[16 + j], w[16 + j]};
            v2f wb = (v2f){w[32 + j], w[32 + j]};
            ai[j][0] = __builtin_elementwise_fma(wi, xlo, ai[j][0]);
            ai[j][1] = __builtin_elementwise_fma(wi, xhi, ai[j][1]);
            ad[j][0] = __builtin_elementwise_fma(wd, xlo, ad[j][0]);
            ad[j][1] = __builtin_elementwise_fma(wd, xhi, ad[j][1]);
            ab[j][0] = __builtin_elementwise_fma(wb, xlo, ab[j][0]);
            ab[j][1] = __builtin_elementwise_fma(wb, xhi, ab[j][1]);
        }
    }

    const float lam = lam_p[0], alpha = alpha_p[0];
    const int base = b * (HID * HW) + p0;
    const int lseg = tid & 31;                             // lane within 32-lane row segment
#pragma unroll
    for (int j = 0; j < 16; ++j) {
        int o = og * 16 + j;
        float bi = sbi[j], bd = sbd[j], bb2 = sbb[j], nA = snA[j];
        float adv[4] = {ad[j][0].x, ad[j][0].y, ad[j][1].x, ad[j][1].y};
        float aiv[4] = {ai[j][0].x, ai[j][0].y, ai[j][1].x, ai[j][1].y};
        float abv[4] = {ab[j][0].x, ab[j][0].y, ab[j][1].x, ab[j][1].y};
        float Ao[4], bo[4];
#pragma unroll
        for (int k = 0; k < 4; ++k) {
            float dv = adv[k] + bd + lam * pus[k];
            float d  = fmaxf(dv, 0.f) + log1pf(expf(-fabsf(dv)));   // softplus
            Ao[k] = expf(d * nA);
            float feat = aiv[k] + bi;
            float Bk = (abv[k] + bb2) * (1.f + alpha * pus[k]);
            bo[k] = d * Bk * feat;
        }
        *(h4*)(Abar + base + o * HW) =
            (h4){(_Float16)Ao[0], (_Float16)Ao[1], (_Float16)Ao[2], (_Float16)Ao[3]};
        *(h4*)(bbuf + base + o * HW) =
            (h4){(_Float16)bo[0], (_Float16)bo[1], (_Float16)bo[2], (_Float16)bo[3]};
        // ---- h-scan for this channel: 32-lane segmented shuffle scan over the row ----
        float c0 = Ao[0], c1 = c0 * Ao[1], c2 = c1 * Ao[2], c3 = c2 * Ao[3];
        float Lp = c3;
#pragma unroll
        for (int off = 1; off < 32; off <<= 1) {
            float tt = __shfl_up(Lp, off, 32);
            if (lseg >= off) Lp *= tt;
        }
        float ep = __shfl_up(Lp, 1, 32);
        if (lseg == 0) ep = 1.f;
        float P0 = ep * c0, P1 = ep * c1, P2 = ep * c2, P3 = ep * c3;
        float q0 = bo[0] / fmaxf(P0, 1e-8f);
        float q1 = bo[1] / fmaxf(P1, 1e-8f);
        float q2 = bo[2] / fmaxf(P2, 1e-8f);
        float q3 = bo[3] / fmaxf(P3, 1e-8f);
        float s0 = q0, s1 = s0 + q1, s2 = s1 + q2, s3 = s2 + q3;
        float Ls = s3;
#pragma unroll
        for (int off = 1; off < 32; off <<= 1) {
            float tt = __shfl_up(Ls, off, 32);
            if (lseg >= off) Ls += tt;
        }
        float es = __shfl_up(Ls, 1, 32);
        if (lseg == 0) es = 0.f;
        *(h4*)(hsum + base + o * HW) = (h4){(_Float16)(P0 * (es + s0)),
                                            (_Float16)(P1 * (es + s1)),
                                            (_Float16)(P2 * (es + s2)),
                                            (_Float16)(P3 * (es + s3))};
    }
}

// ========= L2: vertical scan; writes final sum = hsum + vsum (fp16 fields, fp32 math) ========
__global__ __launch_bounds__(256) void vscan_kernel(const _Float16* __restrict__ Abar,
                                                    const _Float16* __restrict__ bbuf,
                                                    const _Float16* __restrict__ hsum,
                                                    _Float16* __restrict__ sum,
                                                    const float* __restrict__ gamma_p) {
    if (gamma_p[0] == 0.f) return;
    int idx = blockIdx.x * 256 + threadIdx.x;              // [0,131072): (plane)*WD + col
    int base = (idx >> 7) * HW + (idx & 127);
    float P = 1.f, s = 0.f;
    for (int i = 0; i < HD; ++i) {
        int off = base + i * WD;
        float a  = (float)Abar[off];
        float bv = (float)bbuf[off];
        float hv = (float)hsum[off];
        P *= a;
        s += bv / fmaxf(P, 1e-8f);
        sum[off] = (_Float16)(hv + P * s);
    }
}

// ====== L3: pure 1x1 conv + residual: out0 = x + g*(W_out . sum + b_out) ======
__global__ __launch_bounds__(256, 2) void conv_kernel(const _Float16* __restrict__ sum,
                                                      const float* __restrict__ x,
                                                      const float* __restrict__ W_out,
                                                      const float* __restrict__ b_out,
                                                      const float* __restrict__ gamma_p,
                                                      float* __restrict__ out0) {
    float g = gamma_p[0];
    if (g == 0.f) return;
    __shared__ float sw[HID][16];                          // 8 KB
    int bx = blockIdx.x, og = blockIdx.y, b = blockIdx.z;
    int tid = threadIdx.x;
    int p0 = bx * 1024 + tid * 4;
    for (int idx = tid; idx < HID * 16; idx += 256) {
        int c = idx >> 4, j = idx & 15;
        sw[c][j] = W_out[(og * 16 + j) * HID + c];
    }
    __syncthreads();
    v2f acc[16][2];
#pragma unroll
    for (int j = 0; j < 16; ++j) {
        acc[j][0] = (v2f){0.f, 0.f};
        acc[j][1] = (v2f){0.f, 0.f};
    }
    const _Float16* sb = sum + b * (HID * HW) + p0;
    for (int c = 0; c < HID; ++c) {
        h4 sv = *(const h4*)(sb + c * HW);
        v2f lo = (v2f){(float)sv[0], (float)sv[1]};
        v2f hi = (v2f){(float)sv[2], (float)sv[3]};
        const float* w = sw[c];
#pragma unroll
        for (int j = 0; j < 16; ++j) {
            v2f wj = (v2f){w[j], w[j]};
            acc[j][0] = __builtin_elementwise_fma(wj, lo, acc[j][0]);
            acc[j][1] = __builtin_elementwise_fma(wj, hi, acc[j][1]);
        }
    }
#pragma unroll
    for (int j = 0; j < 16; ++j) {
        int o = og * 16 + j;
        float bo = b_out[o];
        int oi = b * (CIN * HW) + o * HW + p0;
        float4 xv = *(const float4*)(x + oi);
        float4 o4;
        o4.x = xv.x + g * (acc[j][0].x + bo);
        o4.y = xv.y + g * (acc[j][0].y + bo);
        o4.z = xv.z + g * (acc[j][1].x + bo);
        o4.w = xv.w + g * (acc[j][1].y + bo);
        *(float4*)(out0 + oi) = o4;
    }
}

extern "C" void kernel_launch(void* const* d_in, const int* in_sizes, int n_in,
                              void* d_out, int out_size, void* d_ws, size_t ws_size,
                              hipStream_t stream) {
    const float* x       = (const float*)d_in[0];
    const float* prior   = (const float*)d_in[1];
    const float* W_in    = (const float*)d_in[2];
    const float* b_in    = (const float*)d_in[3];
    const float* W_out   = (const float*)d_in[4];
    const float* b_out   = (const float*)d_in[5];
    const float* W_delta = (const float*)d_in[6];
    const float* b_delta = (const float*)d_in[7];
    const float* W_B     = (const float*)d_in[8];
    const float* b_B     = (const float*)d_in[9];
    const float* lam     = (const float*)d_in[10];
    const float* alpha   = (const float*)d_in[11];
    const float* A       = (const float*)d_in[12];
    const float* gamma   = (const float*)d_in[13];

    float* out0 = (float*)d_out;                       // [8,64,128,128]
    float* out1 = (float*)d_out + NB * CIN * HW;       // prior_up [8,1,128,128]

    const size_t FIELD = (size_t)NB * HID * HW;        // 16,777,216 elements
    _Float16* Abar = (_Float16*)d_ws;                  // four fp16 fields: 4 * 33.5 MB
    _Float16* bbuf = Abar + FIELD;
    _Float16* hsum = bbuf + FIELD;
    _Float16* sumb = hsum + FIELD;

    // L1: fused upsample + weight compose + gate + h-scan (also handles gamma==0 copy)
    gate_kernel<<<dim3(16, 8, NB), dim3(256), 0, stream>>>(
        x, prior, W_in, b_in, W_delta, b_delta, W_B, b_B,
        lam, alpha, A, gamma, Abar, bbuf, hsum, out0, out1);
    // L2: vertical scan, emits final sum = hsum + vsum
    vscan_kernel<<<dim3(512), dim3(256), 0, stream>>>(Abar, bbuf, hsum, sumb, gamma);
    // L3: pure output conv + residual
    conv_kernel<<<dim3(16, 4, NB), dim3(256), 0, stream>>>(
        sumb, x, W_out, b_out, gamma, out0);
}

// Round 8
// 110.172 us; speedup vs baseline: 1.0172x; 1.0172x over previous
//
#include <hip/hip_runtime.h>
#include <math.h>

#define HID 128
#define CIN 64
#define NB 8
#define HD 128
#define WD 128
#define HW (HD*WD)   // 16384

typedef float v2f __attribute__((ext_vector_type(2)));
typedef _Float16 h2 __attribute__((ext_vector_type(2)));
typedef _Float16 h4 __attribute__((ext_vector_type(4)));

// ======= L1: fused gate (round-6 winner, unchanged) =======
__global__ __launch_bounds__(256, 2) void gate_kernel(const float* __restrict__ x,
                                                      const float* __restrict__ prior,
                                                      const float* __restrict__ W_in,
                                                      const float* __restrict__ b_in,
                                                      const float* __restrict__ W_delta,
                                                      const float* __restrict__ b_delta,
                                                      const float* __restrict__ W_B,
                                                      const float* __restrict__ b_B,
                                                      const float* __restrict__ lam_p,
                                                      const float* __restrict__ alpha_p,
                                                      const float* __restrict__ A,
                                                      const float* __restrict__ gamma_p,
                                                      _Float16* __restrict__ Abar,
                                                      _Float16* __restrict__ bbuf,
                                                      float* __restrict__ out0,
                                                      float* __restrict__ out1) {
    __shared__ float sw[CIN][48];                          // {W_in | Wd' | Wb'} x 16 outs, 12 KB
    __shared__ float sbd[16], sbb[16], snA[16], sbi[16];
    const int bx = blockIdx.x, og = blockIdx.y, b = blockIdx.z;
    const int tid = threadIdx.x;
    const int p0 = bx * 1024 + tid * 4;
    const float g = gamma_p[0];

    // ---- inline prior upsample for this thread's 4 px (same row) ----
    const float scale = 63.0f / 127.0f;
    int i = p0 >> 7;
    float ys = i * scale;
    int y0 = (int)floorf(ys); int y1 = min(y0 + 1, 63);
    float wy = ys - (float)y0;
    const float* pp = prior + b * 4096;
    int col0 = p0 & 127;
    float pus[4];
#pragma unroll
    for (int k = 0; k < 4; ++k) {
        float xs = (col0 + k) * scale;
        int x0 = (int)floorf(xs); int x1 = min(x0 + 1, 63);
        float wx = xs - (float)x0;
        float v00 = pp[y0 * 64 + x0], v01 = pp[y0 * 64 + x1];
        float v10 = pp[y1 * 64 + x0], v11 = pp[y1 * 64 + x1];
        float r0 = v00 * (1.f - wy) + v10 * wy;
        float r1 = v01 * (1.f - wy) + v11 * wy;
        float v = r0 * (1.f - wx) + r1 * wx;
        pus[k] = fminf(fmaxf(v, -1.f), 1.f);
    }
    if (og == 0)
        *(float4*)(out1 + b * HW + p0) = make_float4(pus[0], pus[1], pus[2], pus[3]);

    // ---- gamma==0: out0 = x (this block's 8-channel slab), done ----
    if (g == 0.f) {
        const float* xs0 = x + b * (CIN * HW) + (og * 8) * HW + p0;
        float* o0 = out0 + b * (CIN * HW) + (og * 8) * HW + p0;
#pragma unroll
        for (int ch = 0; ch < 8; ++ch)
            *(float4*)(o0 + ch * HW) = *(const float4*)(xs0 + ch * HW);
        return;
    }

    // ---- compose weights for this block's 16 out-channels into LDS ----
#pragma unroll
    for (int k = 0; k < 4; ++k) {
        int e = tid + k * 256;                             // [0,1024): c = e>>4, j = e&15
        int c = e >> 4, j = e & 15;
        int o = og * 16 + j;
        float wd = 0.f, wb = 0.f;
        for (int h = 0; h < HID; ++h) {
            float wi = W_in[h * CIN + c];
            wd = fmaf(W_delta[o * HID + h], wi, wd);
            wb = fmaf(W_B[o * HID + h], wi, wb);
        }
        sw[c][j]      = W_in[o * CIN + c];
        sw[c][16 + j] = wd;
        sw[c][32 + j] = wb;
    }
    if (tid < 16) {
        int o = og * 16 + tid;
        float sd = b_delta[o], sb = b_B[o];
        for (int h = 0; h < HID; ++h) {
            float bi = b_in[h];
            sd = fmaf(W_delta[o * HID + h], bi, sd);
            sb = fmaf(W_B[o * HID + h], bi, sb);
        }
        sbd[tid] = sd; sbb[tid] = sb;
        snA[tid] = -expf(A[o]); sbi[tid] = b_in[o];
    }
    __syncthreads();

    // ---- main GEMV loop (K=64), packed fp32 ----
    v2f ai[16][2], ad[16][2], ab[16][2];
#pragma unroll
    for (int j = 0; j < 16; ++j)
#pragma unroll
        for (int k = 0; k < 2; ++k) {
            ai[j][k] = (v2f){0.f, 0.f};
            ad[j][k] = (v2f){0.f, 0.f};
            ab[j][k] = (v2f){0.f, 0.f};
        }

    const float* xb = x + b * (CIN * HW) + p0;
    for (int c = 0; c < CIN; ++c) {
        float4 xv = *(const float4*)(xb + c * HW);
        v2f xlo = (v2f){xv.x, xv.y};
        v2f xhi = (v2f){xv.z, xv.w};
        const float* w = sw[c];
#pragma unroll
        for (int j = 0; j < 16; ++j) {
            v2f wi = (v2f){w[j],      w[j]};
            v2f wd = (v2f){w[16 + j], w[16 + j]};
            v2f wb = (v2f){w[32 + j], w[32 + j]};
            ai[j][0] = __builtin_elementwise_fma(wi, xlo, ai[j][0]);
            ai[j][1] = __builtin_elementwise_fma(wi, xhi, ai[j][1]);
            ad[j][0] = __builtin_elementwise_fma(wd, xlo, ad[j][0]);
            ad[j][1] = __builtin_elementwise_fma(wd, xhi, ad[j][1]);
            ab[j][0] = __builtin_elementwise_fma(wb, xlo, ab[j][0]);
            ab[j][1] = __builtin_elementwise_fma(wb, xhi, ab[j][1]);
        }
    }

    const float lam = lam_p[0], alpha = alpha_p[0];
    int base = b * (HID * HW) + p0;
#pragma unroll
    for (int j = 0; j < 16; ++j) {
        int o = og * 16 + j;
        float bi = sbi[j], bd = sbd[j], bb2 = sbb[j], nA = snA[j];
        float adv[4] = {ad[j][0].x, ad[j][0].y, ad[j][1].x, ad[j][1].y};
        float aiv[4] = {ai[j][0].x, ai[j][0].y, ai[j][1].x, ai[j][1].y};
        float abv[4] = {ab[j][0].x, ab[j][0].y, ab[j][1].x, ab[j][1].y};
        float Ao[4], bo[4];
#pragma unroll
        for (int k = 0; k < 4; ++k) {
            float dv = adv[k] + bd + lam * pus[k];
            float d  = fmaxf(dv, 0.f) + log1pf(expf(-fabsf(dv)));   // softplus
            Ao[k] = expf(d * nA);
            float feat = aiv[k] + bi;
            float Bk = (abv[k] + bb2) * (1.f + alpha * pus[k]);
            bo[k] = d * Bk * feat;
        }
        *(h4*)(Abar + base + o * HW) =
            (h4){(_Float16)Ao[0], (_Float16)Ao[1], (_Float16)Ao[2], (_Float16)Ao[3]};
        *(h4*)(bbuf + base + o * HW) =
            (h4){(_Float16)bo[0], (_Float16)bo[1], (_Float16)bo[2], (_Float16)bo[3]};
    }
}

// ======= L2: fused v+h scan, one (b,c) plane per block =======
// Phase V: thread-per-column scan -> vres (fp16 LDS, 32 KB).
// Phase H: wave-shuffle scan per row (A,b re-read L1/L2-hot), add vres, write sum once.
__global__ __launch_bounds__(256, 4) void scan_plane_kernel(const _Float16* __restrict__ Abar,
                                                            const _Float16* __restrict__ bbuf,
                                                            _Float16* __restrict__ sum,
                                                            const float* __restrict__ gamma_p) {
    if (gamma_p[0] == 0.f) return;
    __shared__ _Float16 vres[HD][WD];                      // 32 KB -> 4 blocks/CU
    const int plane = blockIdx.x;                          // [0, NB*HID)
    const _Float16* Ab = Abar + (size_t)plane * HW;
    const _Float16* Bb = bbuf + (size_t)plane * HW;
    _Float16* So = sum + (size_t)plane * HW;
    const int t = threadIdx.x;
    if (t < WD) {
        float P = 1.f, s = 0.f;
        for (int i = 0; i < HD; ++i) {
            int off = i * WD + t;
            float a  = (float)Ab[off];
            float bv = (float)Bb[off];
            P *= a;
            s += bv / fmaxf(P, 1e-8f);
            vres[i][t] = (_Float16)(P * s);
        }
    }
    __syncthreads();
    const int lane = t & 63, wv = t >> 6;
    for (int it = 0; it < 32; ++it) {
        int r = wv * 32 + it;
        int coff = r * WD + lane * 2;
        h2 a2 = *(const h2*)(Ab + coff);
        h2 b2 = *(const h2*)(Bb + coff);
        float pa = (float)a2.x, pb0 = (float)a2.y;
        float bx0 = (float)b2.x, bx1 = (float)b2.y;
        float pb = pa * pb0;
        float Lp = pb;
#pragma unroll
        for (int off = 1; off < 64; off <<= 1) {
            float tt = __shfl_up(Lp, off, 64);
            if (lane >= off) Lp *= tt;
        }
        float ep = __shfl_up(Lp, 1, 64);
        if (lane == 0) ep = 1.f;
        float P0 = ep * pa, P1 = ep * pb;
        float q0 = bx0 / fmaxf(P0, 1e-8f);
        float q1 = bx1 / fmaxf(P1, 1e-8f);
        float s0 = q0, s1 = q0 + q1;
        float Ls = s1;
#pragma unroll
        for (int off = 1; off < 64; off <<= 1) {
            float tt = __shfl_up(Ls, off, 64);
            if (lane >= off) Ls += tt;
        }
        float es = __shfl_up(Ls, 1, 64);
        if (lane == 0) es = 0.f;
        float h0 = P0 * (es + s0), h1 = P1 * (es + s1);
        h2 v2 = *(const h2*)(&vres[r][lane * 2]);
        *(h2*)(So + coff) = (h2){(_Float16)(h0 + (float)v2.x),
                                 (_Float16)(h1 + (float)v2.y)};
    }
}

// ====== L3: pure 1x1 conv + residual (round-7 conv, proven): out0 = x + g*(W_out.sum + b) ======
__global__ __launch_bounds__(256, 2) void conv_kernel(const _Float16* __restrict__ sum,
                                                      const float* __restrict__ x,
                                                      const float* __restrict__ W_out,
                                                      const float* __restrict__ b_out,
                                                      const float* __restrict__ gamma_p,
                                                      float* __restrict__ out0) {
    float g = gamma_p[0];
    if (g == 0.f) return;
    __shared__ float sw[HID][16];                          // 8 KB
    int bx = blockIdx.x, og = blockIdx.y, b = blockIdx.z;
    int tid = threadIdx.x;
    int p0 = bx * 1024 + tid * 4;
    for (int idx = tid; idx < HID * 16; idx += 256) {
        int c = idx >> 4, j = idx & 15;
        sw[c][j] = W_out[(og * 16 + j) * HID + c];
    }
    __syncthreads();
    v2f acc[16][2];
#pragma unroll
    for (int j = 0; j < 16; ++j) {
        acc[j][0] = (v2f){0.f, 0.f};
        acc[j][1] = (v2f){0.f, 0.f};
    }
    const _Float16* sb = sum + b * (HID * HW) + p0;
    for (int c = 0; c < HID; ++c) {
        h4 sv = *(const h4*)(sb + c * HW);
        v2f lo = (v2f){(float)sv[0], (float)sv[1]};
        v2f hi = (v2f){(float)sv[2], (float)sv[3]};
        const float* w = sw[c];
#pragma unroll
        for (int j = 0; j < 16; ++j) {
            v2f wj = (v2f){w[j], w[j]};
            acc[j][0] = __builtin_elementwise_fma(wj, lo, acc[j][0]);
            acc[j][1] = __builtin_elementwise_fma(wj, hi, acc[j][1]);
        }
    }
#pragma unroll
    for (int j = 0; j < 16; ++j) {
        int o = og * 16 + j;
        float bo = b_out[o];
        int oi = b * (CIN * HW) + o * HW + p0;
        float4 xv = *(const float4*)(x + oi);
        float4 o4;
        o4.x = xv.x + g * (acc[j][0].x + bo);
        o4.y = xv.y + g * (acc[j][0].y + bo);
        o4.z = xv.z + g * (acc[j][1].x + bo);
        o4.w = xv.w + g * (acc[j][1].y + bo);
        *(float4*)(out0 + oi) = o4;
    }
}

extern "C" void kernel_launch(void* const* d_in, const int* in_sizes, int n_in,
                              void* d_out, int out_size, void* d_ws, size_t ws_size,
                              hipStream_t stream) {
    const float* x       = (const float*)d_in[0];
    const float* prior   = (const float*)d_in[1];
    const float* W_in    = (const float*)d_in[2];
    const float* b_in    = (const float*)d_in[3];
    const float* W_out   = (const float*)d_in[4];
    const float* b_out   = (const float*)d_in[5];
    const float* W_delta = (const float*)d_in[6];
    const float* b_delta = (const float*)d_in[7];
    const float* W_B     = (const float*)d_in[8];
    const float* b_B     = (const float*)d_in[9];
    const float* lam     = (const float*)d_in[10];
    const float* alpha   = (const float*)d_in[11];
    const float* A       = (const float*)d_in[12];
    const float* gamma   = (const float*)d_in[13];

    float* out0 = (float*)d_out;                       // [8,64,128,128]
    float* out1 = (float*)d_out + NB * CIN * HW;       // prior_up [8,1,128,128]

    const size_t FIELD = (size_t)NB * HID * HW;        // 16,777,216 elements
    _Float16* Abar = (_Float16*)d_ws;                  // three fp16 fields: 3 * 33.5 MB
    _Float16* bbuf = Abar + FIELD;
    _Float16* sumb = bbuf + FIELD;

    // L1: fused upsample + weight compose + gate (also handles gamma==0 copy)
    gate_kernel<<<dim3(16, 8, NB), dim3(256), 0, stream>>>(
        x, prior, W_in, b_in, W_delta, b_delta, W_B, b_B,
        lam, alpha, A, gamma, Abar, bbuf, out0, out1);
    // L2: fused v+h scan per plane -> sum (fp16); no vsum field, A/b read L2-hot twice
    scan_plane_kernel<<<dim3(NB * HID), dim3(256), 0, stream>>>(Abar, bbuf, sumb, gamma);
    // L3: pure output conv + residual
    conv_kernel<<<dim3(16, 4, NB), dim3(256), 0, stream>>>(
        sumb, x, W_out, b_out, gamma, out0);
}